// Round 10
// baseline (156.603 us; speedup 1.0000x reference)
//
#include <hip/hip_runtime.h>
#include <hip/hip_bf16.h>

#define SEQ 2048
#define DIM 1024
#define NH 16
#define HD 64
#define MTOT 4096  // B*S

typedef __attribute__((ext_vector_type(8))) short bf16x8;
typedef __attribute__((ext_vector_type(4))) float f32x4;
typedef __attribute__((ext_vector_type(16))) float f32x16;
typedef __attribute__((ext_vector_type(4))) unsigned int u32x4;
typedef __attribute__((ext_vector_type(2))) unsigned int u32x2;

typedef const __attribute__((address_space(1))) void* gptr_t;
typedef __attribute__((address_space(3))) void* sptr_t;

static __device__ __forceinline__ unsigned short f2bf(float f) {
    unsigned int u = __builtin_bit_cast(unsigned int, f);
    return (unsigned short)((u + 0x7FFFu + ((u >> 16) & 1u)) >> 16);
}

#define CVTPK(d, x, y) asm("v_cvt_pk_bf16_f32 %0, %1, %2" : "=v"(d) : "v"(x), "v"(y))
#define PLSWAP(a, b) asm("v_permlane32_swap_b32 %0, %1" : "+v"(a), "+v"(b))

// ---------------- fp32 -> bf16 cast ----------------
__global__ void cast_kernel(const float* __restrict__ in, unsigned short* __restrict__ out, int n) {
    int i = (blockIdx.x * 256 + threadIdx.x) * 4;
    if (i < n) {
        float4 v = *reinterpret_cast<const float4*>(in + i);
        ushort4 o;
        o.x = f2bf(v.x); o.y = f2bf(v.y); o.z = f2bf(v.z); o.w = f2bf(v.w);
        *reinterpret_cast<ushort4*>(out + i) = o;
    }
}

// ---------------- NT GEMM: C[M,N] = A[M,K] * B[N,K]^T (bf16 in) ----------------
template<int MODE>
__global__ __launch_bounds__(256) void gemm_nt(
    const unsigned short* __restrict__ A,
    const unsigned short* __restrict__ B0,
    const unsigned short* __restrict__ B1,
    const unsigned short* __restrict__ B2,
    unsigned short* __restrict__ D0,
    unsigned short* __restrict__ D1,
    unsigned short* __restrict__ D2,
    float* __restrict__ Df,
    const float* __restrict__ bias)
{
    constexpr int K = DIM;
    __shared__ __align__(16) unsigned short Asm[128 * 32];
    __shared__ __align__(16) unsigned short Bsm[128 * 32];

    const int tid = threadIdx.x;
    const int wave = tid >> 6, lane = tid & 63;
    const int wm = wave >> 1, wn = wave & 1;
    const int m0 = blockIdx.y * 128, n0 = blockIdx.x * 128;
    const int fr = lane & 15;

    const unsigned short* Bsel = (MODE == 1 || blockIdx.z == 0) ? B0 : (blockIdx.z == 1 ? B1 : B2);

    const int srow = wave * 32 + (lane >> 2);
    const int schunk = (lane & 3) ^ ((lane >> 3) & 3);
    const size_t abase = (size_t)(m0 + srow) * K + (size_t)schunk * 8;
    const size_t bbase = (size_t)(n0 + srow) * K + (size_t)schunk * 8;

    f32x4 acc[4][4] = {};

    for (int k0 = 0; k0 < K; k0 += 32) {
        #pragma unroll
        for (int c = 0; c < 2; ++c) {
            __builtin_amdgcn_global_load_lds(
                (gptr_t)(A + abase + (size_t)c * 16 * K + k0),
                (sptr_t)((char*)Asm + wave * 2048 + c * 1024), 16, 0, 0);
            __builtin_amdgcn_global_load_lds(
                (gptr_t)(Bsel + bbase + (size_t)c * 16 * K + k0),
                (sptr_t)((char*)Bsm + wave * 2048 + c * 1024), 16, 0, 0);
        }
        __syncthreads();

        bf16x8 af[4], bf[4];
        const int ca = ((lane >> 4) ^ ((fr >> 1) & 3)) * 16;
        #pragma unroll
        for (int i = 0; i < 4; ++i) {
            int ra = wm * 64 + i * 16 + fr;
            int rb = wn * 64 + i * 16 + fr;
            af[i] = *(const bf16x8*)((const char*)Asm + ra * 64 + ca);
            bf[i] = *(const bf16x8*)((const char*)Bsm + rb * 64 + ca);
        }
        #pragma unroll
        for (int i = 0; i < 4; ++i)
            #pragma unroll
            for (int j = 0; j < 4; ++j)
                acc[i][j] = __builtin_amdgcn_mfma_f32_16x16x32_bf16(af[i], bf[j], acc[i][j], 0, 0, 0);
        __syncthreads();
    }

    if (MODE == 0) {
        unsigned short* Dst = (blockIdx.z == 0) ? D0 : (blockIdx.z == 1 ? D1 : D2);
        // Q gets 1/8 * log2(e) folded in (softmax runs in exp2 domain)
        const float scale = (blockIdx.z == 0) ? 0.1803368787f : 1.0f;
        #pragma unroll
        for (int i = 0; i < 4; ++i)
            #pragma unroll
            for (int j = 0; j < 4; ++j)
                #pragma unroll
                for (int r = 0; r < 4; ++r) {
                    int m = m0 + wm * 64 + i * 16 + (lane >> 4) * 4 + r;
                    int n = n0 + wn * 64 + j * 16 + fr;
                    int b = m >> 11, s = m & 2047, h = n >> 6, dh = n & 63;
                    Dst[(((size_t)(b * NH + h)) * SEQ + s) * HD + dh] = f2bf(acc[i][j][r] * scale);
                }
    } else {
        #pragma unroll
        for (int i = 0; i < 4; ++i)
            #pragma unroll
            for (int j = 0; j < 4; ++j)
                #pragma unroll
                for (int r = 0; r < 4; ++r) {
                    int m = m0 + wm * 64 + i * 16 + (lane >> 4) * 4 + r;
                    int n = n0 + wn * 64 + j * 16 + fr;
                    Df[(size_t)m * DIM + n] = acc[i][j][r] + bias[n];
                }
    }
}

// ---------------- flash attention: 64 q/wave, static-max, 2-way kv-split ----------------
// grid: 256 blocks x 512 threads (1 block/CU, 8 waves). Wave owns 64 q-rows (two 32-groups
// A and B); K/V LDS frag reads are SHARED across A and B -> LDS traffic per unit work halved.
// Static MCONST softmax => partials linear: merge = (sum ot)/(sum l).
__global__ __launch_bounds__(512, 2) void attn_kernel(
    const unsigned short* __restrict__ Q,
    const unsigned short* __restrict__ Kg,
    const unsigned short* __restrict__ Vg,
    float* __restrict__ po,   // [2*32][2048][64] f32 unnormalized partial O
    float* __restrict__ ml)   // [2*32*2048] f32 partial l
{
    // 132-byte (33-word) row stride: odd word stride -> conflict-free b32 phases
    __shared__ __align__(16) unsigned short Ksm[2][64 * 66];  // [kv][d]
    __shared__ __align__(16) unsigned short Vsm[2][64 * 66];  // [d][kv] (transposed)

    const int tid = threadIdx.x;
    const int wave = tid >> 6, lane = tid & 63;
    const int lq = lane & 31, hi = lane >> 5;

    const int bid = blockIdx.x;
    const int xcd = bid & 7, slot = bid >> 3;          // slot 0..31
    const int bh = xcd * 4 + (slot & 3);
    const int rest = slot >> 2;                        // 0..7
    const int q0 = (rest >> 1) * 512;
    const int half = rest & 1;
    const int kvbase = half * 1024;

    const unsigned short* Qh = Q + (size_t)bh * SEQ * HD;
    const unsigned short* Kh = Kg + (size_t)bh * SEQ * HD;
    const unsigned short* Vh = Vg + (size_t)bh * SEQ * HD;

    const float MCONST = 12.0f;

    const int qrowA = q0 + wave * 64 + lq;
    const int qrowB = qrowA + 32;
    bf16x8 qfA[4], qfB[4];
    #pragma unroll
    for (int dch = 0; dch < 4; ++dch) {
        qfA[dch] = *(const bf16x8*)(Qh + (size_t)qrowA * HD + dch * 16 + hi * 8);
        qfB[dch] = *(const bf16x8*)(Qh + (size_t)qrowB * HD + dch * 16 + hi * 8);
    }

    f32x16 oA0 = {}, oA1 = {}, oB0 = {}, oB1 = {};
    float lA = 0.f, lB = 0.f;

    // staging thread maps (512 threads stage one 64-kv tile: 16B K + 16B V each)
    const int krow_s = tid >> 3, kch_s = tid & 7;              // K: row, 16B chunk
    const int kvp_s = tid >> 4, sub_s = tid & 1;               // V: kv pair, parity
    const int dch_s = (tid >> 1) & 7;                          // V: 8-d chunk

    bf16x8 sk, sv;
    auto stage_load = [&](int t64) {
        sk = *(const bf16x8*)(Kh + (size_t)(t64 + krow_s) * HD + kch_s * 8);
        sv = *(const bf16x8*)(Vh + (size_t)(t64 + 2 * kvp_s + sub_s) * HD + dch_s * 8);
    };
    auto stage_write = [&](int buf) {
        u32x4 kw = __builtin_bit_cast(u32x4, sk);
        unsigned* kp = (unsigned*)((char*)&Ksm[buf][0] + 132 * krow_s + 16 * kch_s);
        kp[0] = kw[0]; kp[1] = kw[1]; kp[2] = kw[2]; kp[3] = kw[3];
        u32x4 vw = __builtin_bit_cast(u32x4, sv);
        unsigned p0 = (unsigned)__shfl_xor((int)vw[0], 1);
        unsigned p1 = (unsigned)__shfl_xor((int)vw[1], 1);
        unsigned p2 = (unsigned)__shfl_xor((int)vw[2], 1);
        unsigned p3 = (unsigned)__shfl_xor((int)vw[3], 1);
        unsigned ea0 = sub_s ? p2 : vw[0];
        unsigned ea1 = sub_s ? p3 : vw[1];
        unsigned eb0 = sub_s ? vw[2] : p0;
        unsigned eb1 = sub_s ? vw[3] : p1;
        unsigned* vp = (unsigned*)&Vsm[buf][0];
        const int dbase = dch_s * 8 + sub_s * 4;
        vp[33 * (dbase + 0) + kvp_s] = (ea0 & 0xffffu) | (eb0 << 16);
        vp[33 * (dbase + 1) + kvp_s] = (ea0 >> 16) | (eb0 & 0xffff0000u);
        vp[33 * (dbase + 2) + kvp_s] = (ea1 & 0xffffu) | (eb1 << 16);
        vp[33 * (dbase + 3) + kvp_s] = (ea1 >> 16) | (eb1 & 0xffff0000u);
    };

    stage_load(kvbase);
    stage_write(0);
    __syncthreads();

    int cur = 0;
    #pragma unroll 1
    for (int t = 0; t < 16; ++t) {
        if (t < 15) stage_load(kvbase + (t + 1) * 64);   // issue loads early (T14)

        const char* Kb = (const char*)&Ksm[cur][0];
        const char* Vb = (const char*)&Vsm[cur][0];

        // K frags once, shared by both q-groups
        bf16x8 kf0[4], kf1[4];
        #pragma unroll
        for (int dch = 0; dch < 4; ++dch) {
            const unsigned* a0 = (const unsigned*)(Kb + 132 * lq + 32 * dch + 16 * hi);
            const unsigned* a1 = (const unsigned*)(Kb + 132 * (32 + lq) + 32 * dch + 16 * hi);
            u32x4 f0 = {a0[0], a0[1], a0[2], a0[3]};
            u32x4 f1 = {a1[0], a1[1], a1[2], a1[3]};
            kf0[dch] = __builtin_bit_cast(bf16x8, f0);
            kf1[dch] = __builtin_bit_cast(bf16x8, f1);
        }

        bf16x8 pfA[4], pfB[4];

        // ---- group A: QK^T, softmax, P-frags ----
        {
            f32x16 s0, s1;
            #pragma unroll
            for (int r = 0; r < 16; ++r) { s0[r] = -MCONST; s1[r] = -MCONST; }
            __builtin_amdgcn_s_setprio(1);
            #pragma unroll
            for (int dch = 0; dch < 4; ++dch) {
                s0 = __builtin_amdgcn_mfma_f32_32x32x16_bf16(kf0[dch], qfA[dch], s0, 0, 0, 0);
                s1 = __builtin_amdgcn_mfma_f32_32x32x16_bf16(kf1[dch], qfA[dch], s1, 0, 0, 0);
            }
            __builtin_amdgcn_s_setprio(0);
            float sa = 0.f, sb = 0.f, sc = 0.f, sd = 0.f;
            #pragma unroll
            for (int r = 0; r < 16; r += 4) {
                s0[r]     = exp2f(s0[r]);     sa += s0[r];
                s0[r + 1] = exp2f(s0[r + 1]); sb += s0[r + 1];
                s0[r + 2] = exp2f(s0[r + 2]); sc += s0[r + 2];
                s0[r + 3] = exp2f(s0[r + 3]); sd += s0[r + 3];
            }
            #pragma unroll
            for (int r = 0; r < 16; r += 4) {
                s1[r]     = exp2f(s1[r]);     sa += s1[r];
                s1[r + 1] = exp2f(s1[r + 1]); sb += s1[r + 1];
                s1[r + 2] = exp2f(s1[r + 2]); sc += s1[r + 2];
                s1[r + 3] = exp2f(s1[r + 3]); sd += s1[r + 3];
            }
            float ps = (sa + sb) + (sc + sd);
            ps += __shfl_xor(ps, 32);
            lA += ps;
            unsigned w0, w1, w2, w3, w4, w5, w6, w7;
            CVTPK(w0, s0[0], s0[1]);   CVTPK(w1, s0[2], s0[3]);
            CVTPK(w2, s0[4], s0[5]);   CVTPK(w3, s0[6], s0[7]);
            CVTPK(w4, s0[8], s0[9]);   CVTPK(w5, s0[10], s0[11]);
            CVTPK(w6, s0[12], s0[13]); CVTPK(w7, s0[14], s0[15]);
            PLSWAP(w0, w2); PLSWAP(w1, w3); PLSWAP(w4, w6); PLSWAP(w5, w7);
            u32x4 uA = {w0, w1, w2, w3}, uB = {w4, w5, w6, w7};
            pfA[0] = __builtin_bit_cast(bf16x8, uA);
            pfA[1] = __builtin_bit_cast(bf16x8, uB);
            CVTPK(w0, s1[0], s1[1]);   CVTPK(w1, s1[2], s1[3]);
            CVTPK(w2, s1[4], s1[5]);   CVTPK(w3, s1[6], s1[7]);
            CVTPK(w4, s1[8], s1[9]);   CVTPK(w5, s1[10], s1[11]);
            CVTPK(w6, s1[12], s1[13]); CVTPK(w7, s1[14], s1[15]);
            PLSWAP(w0, w2); PLSWAP(w1, w3); PLSWAP(w4, w6); PLSWAP(w5, w7);
            u32x4 uC = {w0, w1, w2, w3}, uD = {w4, w5, w6, w7};
            pfA[2] = __builtin_bit_cast(bf16x8, uC);
            pfA[3] = __builtin_bit_cast(bf16x8, uD);
        }

        // ---- group B: QK^T, softmax, P-frags ----
        {
            f32x16 s0, s1;
            #pragma unroll
            for (int r = 0; r < 16; ++r) { s0[r] = -MCONST; s1[r] = -MCONST; }
            __builtin_amdgcn_s_setprio(1);
            #pragma unroll
            for (int dch = 0; dch < 4; ++dch) {
                s0 = __builtin_amdgcn_mfma_f32_32x32x16_bf16(kf0[dch], qfB[dch], s0, 0, 0, 0);
                s1 = __builtin_amdgcn_mfma_f32_32x32x16_bf16(kf1[dch], qfB[dch], s1, 0, 0, 0);
            }
            __builtin_amdgcn_s_setprio(0);
            float sa = 0.f, sb = 0.f, sc = 0.f, sd = 0.f;
            #pragma unroll
            for (int r = 0; r < 16; r += 4) {
                s0[r]     = exp2f(s0[r]);     sa += s0[r];
                s0[r + 1] = exp2f(s0[r + 1]); sb += s0[r + 1];
                s0[r + 2] = exp2f(s0[r + 2]); sc += s0[r + 2];
                s0[r + 3] = exp2f(s0[r + 3]); sd += s0[r + 3];
            }
            #pragma unroll
            for (int r = 0; r < 16; r += 4) {
                s1[r]     = exp2f(s1[r]);     sa += s1[r];
                s1[r + 1] = exp2f(s1[r + 1]); sb += s1[r + 1];
                s1[r + 2] = exp2f(s1[r + 2]); sc += s1[r + 2];
                s1[r + 3] = exp2f(s1[r + 3]); sd += s1[r + 3];
            }
            float ps = (sa + sb) + (sc + sd);
            ps += __shfl_xor(ps, 32);
            lB += ps;
            unsigned w0, w1, w2, w3, w4, w5, w6, w7;
            CVTPK(w0, s0[0], s0[1]);   CVTPK(w1, s0[2], s0[3]);
            CVTPK(w2, s0[4], s0[5]);   CVTPK(w3, s0[6], s0[7]);
            CVTPK(w4, s0[8], s0[9]);   CVTPK(w5, s0[10], s0[11]);
            CVTPK(w6, s0[12], s0[13]); CVTPK(w7, s0[14], s0[15]);
            PLSWAP(w0, w2); PLSWAP(w1, w3); PLSWAP(w4, w6); PLSWAP(w5, w7);
            u32x4 uA = {w0, w1, w2, w3}, uB = {w4, w5, w6, w7};
            pfB[0] = __builtin_bit_cast(bf16x8, uA);
            pfB[1] = __builtin_bit_cast(bf16x8, uB);
            CVTPK(w0, s1[0], s1[1]);   CVTPK(w1, s1[2], s1[3]);
            CVTPK(w2, s1[4], s1[5]);   CVTPK(w3, s1[6], s1[7]);
            CVTPK(w4, s1[8], s1[9]);   CVTPK(w5, s1[10], s1[11]);
            CVTPK(w6, s1[12], s1[13]); CVTPK(w7, s1[14], s1[15]);
            PLSWAP(w0, w2); PLSWAP(w1, w3); PLSWAP(w4, w6); PLSWAP(w5, w7);
            u32x4 uC = {w0, w1, w2, w3}, uD = {w4, w5, w6, w7};
            pfB[2] = __builtin_bit_cast(bf16x8, uC);
            pfB[3] = __builtin_bit_cast(bf16x8, uD);
        }

        // ---- PV: V frags once, used by both groups ----
        __builtin_amdgcn_s_setprio(1);
        #pragma unroll
        for (int kc = 0; kc < 4; ++kc) {
            const unsigned* v0 = (const unsigned*)(Vb + 132 * lq + 32 * kc + 16 * hi);
            const unsigned* v1 = (const unsigned*)(Vb + 132 * (32 + lq) + 32 * kc + 16 * hi);
            u32x4 g0 = {v0[0], v0[1], v0[2], v0[3]};
            u32x4 g1 = {v1[0], v1[1], v1[2], v1[3]};
            bf16x8 vf0 = __builtin_bit_cast(bf16x8, g0);
            bf16x8 vf1 = __builtin_bit_cast(bf16x8, g1);
            oA0 = __builtin_amdgcn_mfma_f32_32x32x16_bf16(vf0, pfA[kc], oA0, 0, 0, 0);
            oA1 = __builtin_amdgcn_mfma_f32_32x32x16_bf16(vf1, pfA[kc], oA1, 0, 0, 0);
            oB0 = __builtin_amdgcn_mfma_f32_32x32x16_bf16(vf0, pfB[kc], oB0, 0, 0, 0);
            oB1 = __builtin_amdgcn_mfma_f32_32x32x16_bf16(vf1, pfB[kc], oB1, 0, 0, 0);
        }
        __builtin_amdgcn_s_setprio(0);

        if (t < 15) stage_write(cur ^ 1);
        __syncthreads();
        cur ^= 1;
    }

    // ---- write partials (unnormalized O^T + l); merge is linear under static max ----
    const size_t prowA = (size_t)(half * 32 + bh) * SEQ + qrowA;
    const size_t prowB = (size_t)(half * 32 + bh) * SEQ + qrowB;
    float* porA = po + prowA * 64;
    float* porB = po + prowB * 64;
    #pragma unroll
    for (int tg = 0; tg < 4; ++tg) {
        f32x4 a0 = {oA0[4 * tg + 0], oA0[4 * tg + 1], oA0[4 * tg + 2], oA0[4 * tg + 3]};
        *(f32x4*)(porA + 8 * tg + 4 * hi) = a0;
        f32x4 a1 = {oA1[4 * tg + 0], oA1[4 * tg + 1], oA1[4 * tg + 2], oA1[4 * tg + 3]};
        *(f32x4*)(porA + 32 + 8 * tg + 4 * hi) = a1;
        f32x4 b0 = {oB0[4 * tg + 0], oB0[4 * tg + 1], oB0[4 * tg + 2], oB0[4 * tg + 3]};
        *(f32x4*)(porB + 8 * tg + 4 * hi) = b0;
        f32x4 b1 = {oB1[4 * tg + 0], oB1[4 * tg + 1], oB1[4 * tg + 2], oB1[4 * tg + 3]};
        *(f32x4*)(porB + 32 + 8 * tg + 4 * hi) = b1;
    }
    if (hi == 0) { ml[prowA] = lA; ml[prowB] = lB; }
}

// ---------------- merge kv-half partials -> bf16 O [B,S,DIM] ----------------
__global__ __launch_bounds__(256) void merge_kernel(
    const float* __restrict__ po,
    const float* __restrict__ ml,
    unsigned short* __restrict__ ob)
{
    const int gid = blockIdx.x * 256 + threadIdx.x;   // 524288
    const int row = gid >> 3, dch = gid & 7;          // row = bh*2048 + s
    const size_t p1 = row, p2 = (size_t)32 * SEQ + row;
    const float inv = 1.0f / (ml[p1] + ml[p2]);

    f32x4 a0 = *(const f32x4*)(po + p1 * 64 + dch * 8);
    f32x4 a1 = *(const f32x4*)(po + p1 * 64 + dch * 8 + 4);
    f32x4 b0 = *(const f32x4*)(po + p2 * 64 + dch * 8);
    f32x4 b1 = *(const f32x4*)(po + p2 * 64 + dch * 8 + 4);

    unsigned wA, wB, wC, wD;
    CVTPK(wA, (a0[0] + b0[0]) * inv, (a0[1] + b0[1]) * inv);
    CVTPK(wB, (a0[2] + b0[2]) * inv, (a0[3] + b0[3]) * inv);
    CVTPK(wC, (a1[0] + b1[0]) * inv, (a1[1] + b1[1]) * inv);
    CVTPK(wD, (a1[2] + b1[2]) * inv, (a1[3] + b1[3]) * inv);
    u32x4 w = {wA, wB, wC, wD};

    const int bh = row >> 11, s = row & 2047;
    const int b = bh >> 4, h = bh & 15;
    *(u32x4*)(ob + ((size_t)(b * SEQ + s)) * DIM + h * HD + dch * 8) = w;
}

extern "C" void kernel_launch(void* const* d_in, const int* in_sizes, int n_in,
                              void* d_out, int out_size, void* d_ws, size_t ws_size,
                              hipStream_t stream) {
    const float* x  = (const float*)d_in[0];
    const float* Wq = (const float*)d_in[1];
    const float* Wk = (const float*)d_in[2];
    const float* Wv = (const float*)d_in[3];
    const float* Wo = (const float*)d_in[4];
    const float* bo = (const float*)d_in[5];
    float* out = (float*)d_out;

    unsigned short* ws = (unsigned short*)d_ws;
    unsigned short* xb  = ws;
    unsigned short* wqb = xb + (size_t)MTOT * DIM;
    unsigned short* wkb = wqb + (size_t)DIM * DIM;
    unsigned short* wvb = wkb + (size_t)DIM * DIM;
    unsigned short* wob = wvb + (size_t)DIM * DIM;
    unsigned short* qb  = wob + (size_t)DIM * DIM;
    unsigned short* kb  = qb + (size_t)MTOT * DIM;
    unsigned short* vb  = kb + (size_t)MTOT * DIM;
    unsigned short* ob  = vb + (size_t)MTOT * DIM;
    float* po = (float*)(ob + (size_t)MTOT * DIM);   // [2*32*2048][64] f32
    float* ml = po + (size_t)2 * 32 * SEQ * 64;      // [2*32*2048] f32

    cast_kernel<<<dim3(MTOT * DIM / 1024), 256, 0, stream>>>(x, xb, MTOT * DIM);
    cast_kernel<<<dim3(DIM * DIM / 1024), 256, 0, stream>>>(Wq, wqb, DIM * DIM);
    cast_kernel<<<dim3(DIM * DIM / 1024), 256, 0, stream>>>(Wk, wkb, DIM * DIM);
    cast_kernel<<<dim3(DIM * DIM / 1024), 256, 0, stream>>>(Wv, wvb, DIM * DIM);
    cast_kernel<<<dim3(DIM * DIM / 1024), 256, 0, stream>>>(Wo, wob, DIM * DIM);

    gemm_nt<0><<<dim3(DIM / 128, MTOT / 128, 3), 256, 0, stream>>>(
        xb, wqb, wkb, wvb, qb, kb, vb, nullptr, nullptr);

    attn_kernel<<<dim3(256), 512, 0, stream>>>(qb, kb, vb, po, ml);

    merge_kernel<<<dim3(2048), 256, 0, stream>>>(po, ml, ob);

    gemm_nt<1><<<dim3(DIM / 128, MTOT / 128, 1), 256, 0, stream>>>(
        ob, wob, nullptr, nullptr, nullptr, nullptr, nullptr, out, bo);
}

// Round 11
// 153.955 us; speedup vs baseline: 1.0172x; 1.0172x over previous
//
#include <hip/hip_runtime.h>
#include <hip/hip_bf16.h>

#define SEQ 2048
#define DIM 1024
#define NH 16
#define HD 64
#define MTOT 4096  // B*S

typedef __attribute__((ext_vector_type(8))) short bf16x8;
typedef __attribute__((ext_vector_type(4))) float f32x4;
typedef __attribute__((ext_vector_type(16))) float f32x16;
typedef __attribute__((ext_vector_type(4))) unsigned int u32x4;
typedef __attribute__((ext_vector_type(2))) unsigned int u32x2;

typedef const __attribute__((address_space(1))) void* gptr_t;
typedef __attribute__((address_space(3))) void* sptr_t;

static __device__ __forceinline__ unsigned short f2bf(float f) {
    unsigned int u = __builtin_bit_cast(unsigned int, f);
    return (unsigned short)((u + 0x7FFFu + ((u >> 16) & 1u)) >> 16);
}

#define CVTPK(d, x, y) asm("v_cvt_pk_bf16_f32 %0, %1, %2" : "=v"(d) : "v"(x), "v"(y))
#define PLSWAP(a, b) asm("v_permlane32_swap_b32 %0, %1" : "+v"(a), "+v"(b))

// ---------------- fp32 -> bf16 cast ----------------
__global__ void cast_kernel(const float* __restrict__ in, unsigned short* __restrict__ out, int n) {
    int i = (blockIdx.x * 256 + threadIdx.x) * 4;
    if (i < n) {
        float4 v = *reinterpret_cast<const float4*>(in + i);
        ushort4 o;
        o.x = f2bf(v.x); o.y = f2bf(v.y); o.z = f2bf(v.z); o.w = f2bf(v.w);
        *reinterpret_cast<ushort4*>(out + i) = o;
    }
}

// ---------------- NT GEMM: C[M,N] = A[M,K] * B[N,K]^T (bf16 in) ----------------
// MODE 0: z=0: Q (scaled by 0.125*log2e, [bh][s][d]); z=1: K ([bh][s][d]);
//         z=2: V^T in 64-kv tiles: [bh][t=s/64][dh 0..63][kv_in_tile 0..63].
// MODE 1: fp32 out + bias.
template<int MODE>
__global__ __launch_bounds__(256) void gemm_nt(
    const unsigned short* __restrict__ A,
    const unsigned short* __restrict__ B0,
    const unsigned short* __restrict__ B1,
    const unsigned short* __restrict__ B2,
    unsigned short* __restrict__ D0,
    unsigned short* __restrict__ D1,
    unsigned short* __restrict__ D2,
    float* __restrict__ Df,
    const float* __restrict__ bias)
{
    constexpr int K = DIM;
    __shared__ __align__(16) unsigned short Asm[128 * 32];
    __shared__ __align__(16) unsigned short Bsm[128 * 32];

    const int tid = threadIdx.x;
    const int wave = tid >> 6, lane = tid & 63;
    const int wm = wave >> 1, wn = wave & 1;
    const int m0 = blockIdx.y * 128, n0 = blockIdx.x * 128;
    const int fr = lane & 15;

    const unsigned short* Bsel = (MODE == 1 || blockIdx.z == 0) ? B0 : (blockIdx.z == 1 ? B1 : B2);

    const int srow = wave * 32 + (lane >> 2);
    const int schunk = (lane & 3) ^ ((lane >> 3) & 3);
    const size_t abase = (size_t)(m0 + srow) * K + (size_t)schunk * 8;
    const size_t bbase = (size_t)(n0 + srow) * K + (size_t)schunk * 8;

    f32x4 acc[4][4] = {};

    for (int k0 = 0; k0 < K; k0 += 32) {
        #pragma unroll
        for (int c = 0; c < 2; ++c) {
            __builtin_amdgcn_global_load_lds(
                (gptr_t)(A + abase + (size_t)c * 16 * K + k0),
                (sptr_t)((char*)Asm + wave * 2048 + c * 1024), 16, 0, 0);
            __builtin_amdgcn_global_load_lds(
                (gptr_t)(Bsel + bbase + (size_t)c * 16 * K + k0),
                (sptr_t)((char*)Bsm + wave * 2048 + c * 1024), 16, 0, 0);
        }
        __syncthreads();

        bf16x8 af[4], bf[4];
        const int ca = ((lane >> 4) ^ ((fr >> 1) & 3)) * 16;
        #pragma unroll
        for (int i = 0; i < 4; ++i) {
            int ra = wm * 64 + i * 16 + fr;
            int rb = wn * 64 + i * 16 + fr;
            af[i] = *(const bf16x8*)((const char*)Asm + ra * 64 + ca);
            bf[i] = *(const bf16x8*)((const char*)Bsm + rb * 64 + ca);
        }
        #pragma unroll
        for (int i = 0; i < 4; ++i)
            #pragma unroll
            for (int j = 0; j < 4; ++j)
                acc[i][j] = __builtin_amdgcn_mfma_f32_16x16x32_bf16(af[i], bf[j], acc[i][j], 0, 0, 0);
        __syncthreads();
    }

    if (MODE == 0) {
        if (blockIdx.z == 2) {
            // V^T tiled: D2[((bh*32 + t)*64 + dh)*64 + kin], 4 consecutive kv per (i,j) -> 8B store
            #pragma unroll
            for (int i = 0; i < 4; ++i)
                #pragma unroll
                for (int j = 0; j < 4; ++j) {
                    int n = n0 + wn * 64 + j * 16 + fr;
                    int h = n >> 6, dh = n & 63;
                    int mb = m0 + wm * 64 + i * 16 + (lane >> 4) * 4;
                    int b = mb >> 11, s = mb & 2047;
                    int t = s >> 6, kin = s & 63;
                    unsigned wA, wB;
                    CVTPK(wA, acc[i][j][0], acc[i][j][1]);
                    CVTPK(wB, acc[i][j][2], acc[i][j][3]);
                    u32x2 w = {wA, wB};
                    *(u32x2*)(D2 + ((((size_t)(b * NH + h) * 32 + t) * 64 + dh) << 6) + kin) = w;
                }
        } else {
            unsigned short* Dst = (blockIdx.z == 0) ? D0 : D1;
            // Q gets 1/8 * log2(e) folded in (softmax runs in exp2 domain)
            const float scale = (blockIdx.z == 0) ? 0.1803368787f : 1.0f;
            #pragma unroll
            for (int i = 0; i < 4; ++i)
                #pragma unroll
                for (int j = 0; j < 4; ++j)
                    #pragma unroll
                    for (int r = 0; r < 4; ++r) {
                        int m = m0 + wm * 64 + i * 16 + (lane >> 4) * 4 + r;
                        int n = n0 + wn * 64 + j * 16 + fr;
                        int b = m >> 11, s = m & 2047, h = n >> 6, dh = n & 63;
                        Dst[(((size_t)(b * NH + h)) * SEQ + s) * HD + dh] = f2bf(acc[i][j][r] * scale);
                    }
        }
    } else {
        #pragma unroll
        for (int i = 0; i < 4; ++i)
            #pragma unroll
            for (int j = 0; j < 4; ++j)
                #pragma unroll
                for (int r = 0; r < 4; ++r) {
                    int m = m0 + wm * 64 + i * 16 + (lane >> 4) * 4 + r;
                    int n = n0 + wn * 64 + j * 16 + fr;
                    Df[(size_t)m * DIM + n] = acc[i][j][r] + bias[n];
                }
    }
}

// ---------------- flash attention: static-max, b128 XOR-swizzled LDS ----------------
// grid: 256 blocks (1/CU), 512 threads (8 waves x 32 q-rows). R7 structure; all K/V LDS
// traffic is single ds_read_b128/ds_write_b128 with chunk^(row&7) swizzle (conflict-free).
// V^T comes pre-tiled from the GEMM ([bh][t][d][kv]) so staging K and V are identical.
__global__ __launch_bounds__(512, 2) void attn_kernel(
    const unsigned short* __restrict__ Q,
    const unsigned short* __restrict__ Kg,
    const unsigned short* __restrict__ Vt,
    unsigned short* __restrict__ O)
{
    __shared__ __align__(16) unsigned short Ksm[2][64 * 64];  // [kv][d], 128B rows, XOR-swz
    __shared__ __align__(16) unsigned short Vsm[2][64 * 64];  // [d][kv], 128B rows, XOR-swz

    const int tid = threadIdx.x;
    const int wave = tid >> 6, lane = tid & 63;
    const int lq = lane & 31, hi = lane >> 5;

    const int bid = blockIdx.x;
    const int xcd = bid & 7, slot = bid >> 3;
    const int bh = xcd * 4 + (slot & 3);
    const int q0 = (slot >> 2) * 256;

    const unsigned short* Qh = Q + (size_t)bh * SEQ * HD;
    const unsigned short* Kh = Kg + (size_t)bh * SEQ * HD;
    const unsigned short* Vh = Vt + (size_t)bh * SEQ * HD;   // tiled: + t64*64 + d*64 + kv

    const float MCONST = 12.0f;

    const int qrow = q0 + wave * 32 + lq;
    bf16x8 qf[4];
    #pragma unroll
    for (int dch = 0; dch < 4; ++dch)
        qf[dch] = *(const bf16x8*)(Qh + (size_t)qrow * HD + dch * 16 + hi * 8);

    f32x16 ot0 = {}, ot1 = {};          // O^T rows d=0..31 / 32..63, col q=lq
    float l = 0.f;

    // staging map: row = tid>>3 (0..63), chunk = tid&7; same for K and V tiles
    const int srow = tid >> 3, sch = tid & 7;
    const int swoff = 128 * srow + 16 * (sch ^ (srow & 7));   // swizzled LDS byte offset

    bf16x8 sk, sv;
    auto stage_load = [&](int t64) {
        sk = *(const bf16x8*)(Kh + (size_t)(t64 + srow) * HD + sch * 8);
        sv = *(const bf16x8*)(Vh + (size_t)t64 * 64 + srow * 64 + sch * 8);
    };
    auto stage_write = [&](int buf) {
        *(bf16x8*)((char*)&Ksm[buf][0] + swoff) = sk;
        *(bf16x8*)((char*)&Vsm[buf][0] + swoff) = sv;
    };

    stage_load(0);
    stage_write(0);
    __syncthreads();

    const int x7 = lq & 7;   // (lq&7) == ((32+lq)&7)

    int cur = 0;
    #pragma unroll 1
    for (int t = 0; t < SEQ / 64; ++t) {
        if (t + 1 < SEQ / 64) stage_load((t + 1) * 64);   // T14: issue loads early

        const char* Kb = (const char*)&Ksm[cur][0];
        const char* Vb = (const char*)&Vsm[cur][0];

        // S^T - MCONST = mfma(K, Q^T) with C-init = -MCONST
        f32x16 st0, st1;
        #pragma unroll
        for (int r = 0; r < 16; ++r) { st0[r] = -MCONST; st1[r] = -MCONST; }
        __builtin_amdgcn_s_setprio(1);
        #pragma unroll
        for (int dch = 0; dch < 4; ++dch) {
            bf16x8 kf0 = *(const bf16x8*)(Kb + 128 * lq + 16 * ((2 * dch + hi) ^ x7));
            bf16x8 kf1 = *(const bf16x8*)(Kb + 128 * (32 + lq) + 16 * ((2 * dch + hi) ^ x7));
            st0 = __builtin_amdgcn_mfma_f32_32x32x16_bf16(kf0, qf[dch], st0, 0, 0, 0);
            st1 = __builtin_amdgcn_mfma_f32_32x32x16_bf16(kf1, qf[dch], st1, 0, 0, 0);
        }
        __builtin_amdgcn_s_setprio(0);

        // static-max softmax: P = exp2(S - MCONST) directly; 4-way partial sums for ILP
        float sa = 0.f, sb = 0.f, sc = 0.f, sd = 0.f;
        #pragma unroll
        for (int r = 0; r < 16; r += 4) {
            st0[r]     = exp2f(st0[r]);     sa += st0[r];
            st0[r + 1] = exp2f(st0[r + 1]); sb += st0[r + 1];
            st0[r + 2] = exp2f(st0[r + 2]); sc += st0[r + 2];
            st0[r + 3] = exp2f(st0[r + 3]); sd += st0[r + 3];
        }
        #pragma unroll
        for (int r = 0; r < 16; r += 4) {
            st1[r]     = exp2f(st1[r]);     sa += st1[r];
            st1[r + 1] = exp2f(st1[r + 1]); sb += st1[r + 1];
            st1[r + 2] = exp2f(st1[r + 2]); sc += st1[r + 2];
            st1[r + 3] = exp2f(st1[r + 3]); sd += st1[r + 3];
        }
        float ps = (sa + sb) + (sc + sd);
        ps += __shfl_xor(ps, 32);
        l += ps;

        // T12: P -> bf16 B-frags fully in-register (cvt_pk + permlane32_swap)
        bf16x8 pf0, pf1, pf2, pf3;
        {
            unsigned w0, w1, w2, w3, w4, w5, w6, w7;
            CVTPK(w0, st0[0], st0[1]);   CVTPK(w1, st0[2], st0[3]);
            CVTPK(w2, st0[4], st0[5]);   CVTPK(w3, st0[6], st0[7]);
            CVTPK(w4, st0[8], st0[9]);   CVTPK(w5, st0[10], st0[11]);
            CVTPK(w6, st0[12], st0[13]); CVTPK(w7, st0[14], st0[15]);
            PLSWAP(w0, w2); PLSWAP(w1, w3); PLSWAP(w4, w6); PLSWAP(w5, w7);
            u32x4 uA = {w0, w1, w2, w3}, uB = {w4, w5, w6, w7};
            pf0 = __builtin_bit_cast(bf16x8, uA);
            pf1 = __builtin_bit_cast(bf16x8, uB);
        }
        {
            unsigned w0, w1, w2, w3, w4, w5, w6, w7;
            CVTPK(w0, st1[0], st1[1]);   CVTPK(w1, st1[2], st1[3]);
            CVTPK(w2, st1[4], st1[5]);   CVTPK(w3, st1[6], st1[7]);
            CVTPK(w4, st1[8], st1[9]);   CVTPK(w5, st1[10], st1[11]);
            CVTPK(w6, st1[12], st1[13]); CVTPK(w7, st1[14], st1[15]);
            PLSWAP(w0, w2); PLSWAP(w1, w3); PLSWAP(w4, w6); PLSWAP(w5, w7);
            u32x4 uA = {w0, w1, w2, w3}, uB = {w4, w5, w6, w7};
            pf2 = __builtin_bit_cast(bf16x8, uA);
            pf3 = __builtin_bit_cast(bf16x8, uB);
        }

        // O^T += mfma(V^T, P^T)
        __builtin_amdgcn_s_setprio(1);
        #pragma unroll
        for (int kc = 0; kc < 4; ++kc) {
            bf16x8 vf0 = *(const bf16x8*)(Vb + 128 * lq + 16 * ((2 * kc + hi) ^ x7));
            bf16x8 vf1 = *(const bf16x8*)(Vb + 128 * (32 + lq) + 16 * ((2 * kc + hi) ^ x7));
            bf16x8 pfv = (kc == 0) ? pf0 : (kc == 1) ? pf1 : (kc == 2) ? pf2 : pf3;
            ot0 = __builtin_amdgcn_mfma_f32_32x32x16_bf16(vf0, pfv, ot0, 0, 0, 0);
            ot1 = __builtin_amdgcn_mfma_f32_32x32x16_bf16(vf1, pfv, ot1, 0, 0, 0);
        }
        __builtin_amdgcn_s_setprio(0);

        if (t + 1 < SEQ / 64) stage_write(cur ^ 1);
        __syncthreads();
        cur ^= 1;
    }

    // epilogue: O[q][d] = O^T / l, to [B,S,DIM] bf16
    const float inv = 1.0f / l;
    const int b = bh >> 4, h = bh & 15;
    unsigned short* orow = O + ((size_t)(b * SEQ + qrow)) * DIM + h * HD;
    #pragma unroll
    for (int tg = 0; tg < 4; ++tg) {
        unsigned wA, wB;
        CVTPK(wA, ot0[4 * tg + 0] * inv, ot0[4 * tg + 1] * inv);
        CVTPK(wB, ot0[4 * tg + 2] * inv, ot0[4 * tg + 3] * inv);
        u32x2 wlo = {wA, wB};
        *(u32x2*)(orow + 8 * tg + 4 * hi) = wlo;
        CVTPK(wA, ot1[4 * tg + 0] * inv, ot1[4 * tg + 1] * inv);
        CVTPK(wB, ot1[4 * tg + 2] * inv, ot1[4 * tg + 3] * inv);
        u32x2 whi = {wA, wB};
        *(u32x2*)(orow + 32 + 8 * tg + 4 * hi) = whi;
    }
}

extern "C" void kernel_launch(void* const* d_in, const int* in_sizes, int n_in,
                              void* d_out, int out_size, void* d_ws, size_t ws_size,
                              hipStream_t stream) {
    const float* x  = (const float*)d_in[0];
    const float* Wq = (const float*)d_in[1];
    const float* Wk = (const float*)d_in[2];
    const float* Wv = (const float*)d_in[3];
    const float* Wo = (const float*)d_in[4];
    const float* bo = (const float*)d_in[5];
    float* out = (float*)d_out;

    unsigned short* ws = (unsigned short*)d_ws;
    unsigned short* xb  = ws;
    unsigned short* wqb = xb + (size_t)MTOT * DIM;
    unsigned short* wkb = wqb + (size_t)DIM * DIM;
    unsigned short* wvb = wkb + (size_t)DIM * DIM;
    unsigned short* wob = wvb + (size_t)DIM * DIM;
    unsigned short* qb  = wob + (size_t)DIM * DIM;
    unsigned short* kb  = qb + (size_t)MTOT * DIM;
    unsigned short* vtb = kb + (size_t)MTOT * DIM;   // V^T tiled: [bh][t][d][kv]
    unsigned short* ob  = vtb + (size_t)MTOT * DIM;

    cast_kernel<<<dim3(MTOT * DIM / 1024), 256, 0, stream>>>(x, xb, MTOT * DIM);
    cast_kernel<<<dim3(DIM * DIM / 1024), 256, 0, stream>>>(Wq, wqb, DIM * DIM);
    cast_kernel<<<dim3(DIM * DIM / 1024), 256, 0, stream>>>(Wk, wkb, DIM * DIM);
    cast_kernel<<<dim3(DIM * DIM / 1024), 256, 0, stream>>>(Wv, wvb, DIM * DIM);
    cast_kernel<<<dim3(DIM * DIM / 1024), 256, 0, stream>>>(Wo, wob, DIM * DIM);

    gemm_nt<0><<<dim3(DIM / 128, MTOT / 128, 3), 256, 0, stream>>>(
        xb, wqb, wkb, wvb, qb, kb, vtb, nullptr, nullptr);

    attn_kernel<<<dim3(256), 512, 0, stream>>>(qb, kb, vtb, ob);

    gemm_nt<1><<<dim3(DIM / 128, MTOT / 128, 1), 256, 0, stream>>>(
        ob, wob, nullptr, nullptr, nullptr, nullptr, nullptr, out, bo);
}

// Round 12
// 130.169 us; speedup vs baseline: 1.2031x; 1.1827x over previous
//
#include <hip/hip_runtime.h>
#include <hip/hip_bf16.h>

#define SEQ 2048
#define DIM 1024
#define NH 16
#define HD 64
#define MTOT 4096  // B*S

typedef __attribute__((ext_vector_type(8))) short bf16x8;
typedef __attribute__((ext_vector_type(4))) float f32x4;
typedef __attribute__((ext_vector_type(16))) float f32x16;
typedef __attribute__((ext_vector_type(4))) unsigned int u32x4;
typedef __attribute__((ext_vector_type(2))) unsigned int u32x2;

typedef const __attribute__((address_space(1))) void* gptr_t;
typedef __attribute__((address_space(3))) void* sptr_t;

static __device__ __forceinline__ unsigned short f2bf(float f) {
    unsigned int u = __builtin_bit_cast(unsigned int, f);
    return (unsigned short)((u + 0x7FFFu + ((u >> 16) & 1u)) >> 16);
}

#define CVTPK(d, x, y) asm("v_cvt_pk_bf16_f32 %0, %1, %2" : "=v"(d) : "v"(x), "v"(y))
#define PLSWAP(a, b) asm("v_permlane32_swap_b32 %0, %1" : "+v"(a), "+v"(b))

// ---------------- fused fp32 -> bf16 cast (x + 4 weights, one launch) ----------------
__global__ __launch_bounds__(256) void cast_all(
    const float* __restrict__ x,  const float* __restrict__ wq,
    const float* __restrict__ wk, const float* __restrict__ wv,
    const float* __restrict__ wo,
    unsigned short* __restrict__ xb,  unsigned short* __restrict__ wqb,
    unsigned short* __restrict__ wkb, unsigned short* __restrict__ wvb,
    unsigned short* __restrict__ wob)
{
    int bid = blockIdx.x;
    const float* src;
    unsigned short* dst;
    int boff;
    if (bid < 4096) { src = x; dst = xb; boff = bid; }
    else {
        int w = (bid - 4096) >> 10, r = (bid - 4096) & 1023;
        src = (w == 0) ? wq : (w == 1) ? wk : (w == 2) ? wv : wo;
        dst = (w == 0) ? wqb : (w == 1) ? wkb : (w == 2) ? wvb : wob;
        boff = r;
    }
    size_t i = ((size_t)boff * 256 + threadIdx.x) * 4;
    float4 v = *reinterpret_cast<const float4*>(src + i);
    ushort4 o;
    o.x = f2bf(v.x); o.y = f2bf(v.y); o.z = f2bf(v.z); o.w = f2bf(v.w);
    *reinterpret_cast<ushort4*>(dst + i) = o;
}

// ---------------- NT GEMM: C[M,N] = A[M,K] * B[N,K]^T (bf16 in) ----------------
// MODE 0: z in {0,1,2} selects B/W and dst (q/k/v); scatter to [B,H,S,hd], Q scaled 0.125*log2e.
// MODE 1: fp32 out + bias.
template<int MODE>
__global__ __launch_bounds__(256) void gemm_nt(
    const unsigned short* __restrict__ A,
    const unsigned short* __restrict__ B0,
    const unsigned short* __restrict__ B1,
    const unsigned short* __restrict__ B2,
    unsigned short* __restrict__ D0,
    unsigned short* __restrict__ D1,
    unsigned short* __restrict__ D2,
    float* __restrict__ Df,
    const float* __restrict__ bias)
{
    constexpr int K = DIM;
    __shared__ __align__(16) unsigned short Asm[128 * 32];
    __shared__ __align__(16) unsigned short Bsm[128 * 32];

    const int tid = threadIdx.x;
    const int wave = tid >> 6, lane = tid & 63;
    const int wm = wave >> 1, wn = wave & 1;
    const int m0 = blockIdx.y * 128, n0 = blockIdx.x * 128;
    const int fr = lane & 15;

    const unsigned short* Bsel = (MODE == 1 || blockIdx.z == 0) ? B0 : (blockIdx.z == 1 ? B1 : B2);

    const int srow = wave * 32 + (lane >> 2);
    const int schunk = (lane & 3) ^ ((lane >> 3) & 3);
    const size_t abase = (size_t)(m0 + srow) * K + (size_t)schunk * 8;
    const size_t bbase = (size_t)(n0 + srow) * K + (size_t)schunk * 8;

    f32x4 acc[4][4] = {};

    for (int k0 = 0; k0 < K; k0 += 32) {
        #pragma unroll
        for (int c = 0; c < 2; ++c) {
            __builtin_amdgcn_global_load_lds(
                (gptr_t)(A + abase + (size_t)c * 16 * K + k0),
                (sptr_t)((char*)Asm + wave * 2048 + c * 1024), 16, 0, 0);
            __builtin_amdgcn_global_load_lds(
                (gptr_t)(Bsel + bbase + (size_t)c * 16 * K + k0),
                (sptr_t)((char*)Bsm + wave * 2048 + c * 1024), 16, 0, 0);
        }
        __syncthreads();

        bf16x8 af[4], bf[4];
        const int ca = ((lane >> 4) ^ ((fr >> 1) & 3)) * 16;
        #pragma unroll
        for (int i = 0; i < 4; ++i) {
            int ra = wm * 64 + i * 16 + fr;
            int rb = wn * 64 + i * 16 + fr;
            af[i] = *(const bf16x8*)((const char*)Asm + ra * 64 + ca);
            bf[i] = *(const bf16x8*)((const char*)Bsm + rb * 64 + ca);
        }
        #pragma unroll
        for (int i = 0; i < 4; ++i)
            #pragma unroll
            for (int j = 0; j < 4; ++j)
                acc[i][j] = __builtin_amdgcn_mfma_f32_16x16x32_bf16(af[i], bf[j], acc[i][j], 0, 0, 0);
        __syncthreads();
    }

    if (MODE == 0) {
        unsigned short* Dst = (blockIdx.z == 0) ? D0 : (blockIdx.z == 1 ? D1 : D2);
        // Q gets 1/8 * log2(e) folded in (softmax runs in exp2 domain)
        const float scale = (blockIdx.z == 0) ? 0.1803368787f : 1.0f;
        #pragma unroll
        for (int i = 0; i < 4; ++i)
            #pragma unroll
            for (int j = 0; j < 4; ++j)
                #pragma unroll
                for (int r = 0; r < 4; ++r) {
                    int m = m0 + wm * 64 + i * 16 + (lane >> 4) * 4 + r;
                    int n = n0 + wn * 64 + j * 16 + fr;
                    int b = m >> 11, s = m & 2047, h = n >> 6, dh = n & 63;
                    Dst[(((size_t)(b * NH + h)) * SEQ + s) * HD + dh] = f2bf(acc[i][j][r] * scale);
                }
    } else {
        #pragma unroll
        for (int i = 0; i < 4; ++i)
            #pragma unroll
            for (int j = 0; j < 4; ++j)
                #pragma unroll
                for (int r = 0; r < 4; ++r) {
                    int m = m0 + wm * 64 + i * 16 + (lane >> 4) * 4 + r;
                    int n = n0 + wn * 64 + j * 16 + fr;
                    Df[(size_t)m * DIM + n] = acc[i][j][r] + bias[n];
                }
    }
}

// ---------------- V transpose: [bh][s][d] -> tiled V^T [bh][t=s/64][d][kv=s&63] ----------------
// 1024 blocks (bh*32 + t) x 256 threads. Coalesced load -> shfl-pair pack (R2-verified) ->
// 132B-stride LDS -> coalesced b128 read -> coalesced 16B store.
__global__ __launch_bounds__(256) void vtrans_kernel(
    const unsigned short* __restrict__ V, unsigned short* __restrict__ Vt)
{
    __shared__ __align__(16) unsigned short T[64 * 66];
    const int bh = blockIdx.x >> 5, t = blockIdx.x & 31;
    const unsigned short* src = V + ((size_t)bh * SEQ + t * 64) * HD;
    const int tid = threadIdx.x;

    #pragma unroll
    for (int it = 0; it < 2; ++it) {
        int vt = tid + it * 256;
        int kvp = vt >> 4, sub = vt & 1, dch = (vt >> 1) & 7;
        bf16x8 sv = *(const bf16x8*)(src + (size_t)(2 * kvp + sub) * HD + dch * 8);
        u32x4 vw = __builtin_bit_cast(u32x4, sv);
        unsigned p0 = (unsigned)__shfl_xor((int)vw[0], 1);
        unsigned p1 = (unsigned)__shfl_xor((int)vw[1], 1);
        unsigned p2 = (unsigned)__shfl_xor((int)vw[2], 1);
        unsigned p3 = (unsigned)__shfl_xor((int)vw[3], 1);
        unsigned ea0 = sub ? p2 : vw[0];   // even-kv words for this lane's d range
        unsigned ea1 = sub ? p3 : vw[1];
        unsigned eb0 = sub ? vw[2] : p0;   // odd-kv words
        unsigned eb1 = sub ? vw[3] : p1;
        unsigned* vp = (unsigned*)&T[0];
        const int dbase = dch * 8 + sub * 4;
        vp[33 * (dbase + 0) + kvp] = (ea0 & 0xffffu) | (eb0 << 16);
        vp[33 * (dbase + 1) + kvp] = (ea0 >> 16) | (eb0 & 0xffff0000u);
        vp[33 * (dbase + 2) + kvp] = (ea1 & 0xffffu) | (eb1 << 16);
        vp[33 * (dbase + 3) + kvp] = (ea1 >> 16) | (eb1 & 0xffff0000u);
    }
    __syncthreads();

    const int drow = tid >> 2, kch = tid & 3;
    unsigned short* dst = Vt + (((size_t)(bh * 32 + t) * 64) << 6);
    bf16x8 a = *(const bf16x8*)((const char*)&T[0] + 132 * drow + 16 * kch);
    bf16x8 b = *(const bf16x8*)((const char*)&T[0] + 132 * drow + 16 * kch + 64);
    *(bf16x8*)(dst + drow * 64 + kch * 8) = a;
    *(bf16x8*)(dst + drow * 64 + (kch + 4) * 8) = b;
}

// ---------------- flash attention: static-max, b128 XOR-swizzled LDS ----------------
// grid: 256 blocks (1/CU), 512 threads (8 waves x 32 q-rows). All K/V LDS traffic is single
// ds_read_b128/ds_write_b128 with chunk^(row&7) swizzle. V^T pre-tiled by vtrans_kernel.
__global__ __launch_bounds__(512, 2) void attn_kernel(
    const unsigned short* __restrict__ Q,
    const unsigned short* __restrict__ Kg,
    const unsigned short* __restrict__ Vt,
    unsigned short* __restrict__ O)
{
    __shared__ __align__(16) unsigned short Ksm[2][64 * 64];  // [kv][d], 128B rows, XOR-swz
    __shared__ __align__(16) unsigned short Vsm[2][64 * 64];  // [d][kv], 128B rows, XOR-swz

    const int tid = threadIdx.x;
    const int wave = tid >> 6, lane = tid & 63;
    const int lq = lane & 31, hi = lane >> 5;

    const int bid = blockIdx.x;
    const int xcd = bid & 7, slot = bid >> 3;
    const int bh = xcd * 4 + (slot & 3);
    const int q0 = (slot >> 2) * 256;

    const unsigned short* Qh = Q + (size_t)bh * SEQ * HD;
    const unsigned short* Kh = Kg + (size_t)bh * SEQ * HD;
    const unsigned short* Vh = Vt + (size_t)bh * SEQ * HD;   // tiled: + t64*64 + d*64 + kv

    const float MCONST = 12.0f;

    const int qrow = q0 + wave * 32 + lq;
    bf16x8 qf[4];
    #pragma unroll
    for (int dch = 0; dch < 4; ++dch)
        qf[dch] = *(const bf16x8*)(Qh + (size_t)qrow * HD + dch * 16 + hi * 8);

    f32x16 ot0 = {}, ot1 = {};          // O^T rows d=0..31 / 32..63, col q=lq
    float l = 0.f;

    // staging map: row = tid>>3 (0..63), chunk = tid&7; same for K and V tiles
    const int srow = tid >> 3, sch = tid & 7;
    const int swoff = 128 * srow + 16 * (sch ^ (srow & 7));   // swizzled LDS byte offset

    bf16x8 sk, sv;
    auto stage_load = [&](int t64) {
        sk = *(const bf16x8*)(Kh + (size_t)(t64 + srow) * HD + sch * 8);
        sv = *(const bf16x8*)(Vh + (size_t)t64 * 64 + srow * 64 + sch * 8);
    };
    auto stage_write = [&](int buf) {
        *(bf16x8*)((char*)&Ksm[buf][0] + swoff) = sk;
        *(bf16x8*)((char*)&Vsm[buf][0] + swoff) = sv;
    };

    stage_load(0);
    stage_write(0);
    __syncthreads();

    const int x7 = lq & 7;   // (lq&7) == ((32+lq)&7)

    int cur = 0;
    #pragma unroll 1
    for (int t = 0; t < SEQ / 64; ++t) {
        if (t + 1 < SEQ / 64) stage_load((t + 1) * 64);   // T14: issue loads early

        const char* Kb = (const char*)&Ksm[cur][0];
        const char* Vb = (const char*)&Vsm[cur][0];

        // S^T - MCONST = mfma(K, Q^T) with C-init = -MCONST
        f32x16 st0, st1;
        #pragma unroll
        for (int r = 0; r < 16; ++r) { st0[r] = -MCONST; st1[r] = -MCONST; }
        __builtin_amdgcn_s_setprio(1);
        #pragma unroll
        for (int dch = 0; dch < 4; ++dch) {
            bf16x8 kf0 = *(const bf16x8*)(Kb + 128 * lq + 16 * ((2 * dch + hi) ^ x7));
            bf16x8 kf1 = *(const bf16x8*)(Kb + 128 * (32 + lq) + 16 * ((2 * dch + hi) ^ x7));
            st0 = __builtin_amdgcn_mfma_f32_32x32x16_bf16(kf0, qf[dch], st0, 0, 0, 0);
            st1 = __builtin_amdgcn_mfma_f32_32x32x16_bf16(kf1, qf[dch], st1, 0, 0, 0);
        }
        __builtin_amdgcn_s_setprio(0);

        // static-max softmax: P = exp2(S - MCONST) directly; 4-way partial sums for ILP
        float sa = 0.f, sb = 0.f, sc = 0.f, sd = 0.f;
        #pragma unroll
        for (int r = 0; r < 16; r += 4) {
            st0[r]     = exp2f(st0[r]);     sa += st0[r];
            st0[r + 1] = exp2f(st0[r + 1]); sb += st0[r + 1];
            st0[r + 2] = exp2f(st0[r + 2]); sc += st0[r + 2];
            st0[r + 3] = exp2f(st0[r + 3]); sd += st0[r + 3];
        }
        #pragma unroll
        for (int r = 0; r < 16; r += 4) {
            st1[r]     = exp2f(st1[r]);     sa += st1[r];
            st1[r + 1] = exp2f(st1[r + 1]); sb += st1[r + 1];
            st1[r + 2] = exp2f(st1[r + 2]); sc += st1[r + 2];
            st1[r + 3] = exp2f(st1[r + 3]); sd += st1[r + 3];
        }
        float ps = (sa + sb) + (sc + sd);
        ps += __shfl_xor(ps, 32);
        l += ps;

        // T12: P -> bf16 B-frags fully in-register (cvt_pk + permlane32_swap)
        bf16x8 pf0, pf1, pf2, pf3;
        {
            unsigned w0, w1, w2, w3, w4, w5, w6, w7;
            CVTPK(w0, st0[0], st0[1]);   CVTPK(w1, st0[2], st0[3]);
            CVTPK(w2, st0[4], st0[5]);   CVTPK(w3, st0[6], st0[7]);
            CVTPK(w4, st0[8], st0[9]);   CVTPK(w5, st0[10], st0[11]);
            CVTPK(w6, st0[12], st0[13]); CVTPK(w7, st0[14], st0[15]);
            PLSWAP(w0, w2); PLSWAP(w1, w3); PLSWAP(w4, w6); PLSWAP(w5, w7);
            u32x4 uA = {w0, w1, w2, w3}, uB = {w4, w5, w6, w7};
            pf0 = __builtin_bit_cast(bf16x8, uA);
            pf1 = __builtin_bit_cast(bf16x8, uB);
        }
        {
            unsigned w0, w1, w2, w3, w4, w5, w6, w7;
            CVTPK(w0, st1[0], st1[1]);   CVTPK(w1, st1[2], st1[3]);
            CVTPK(w2, st1[4], st1[5]);   CVTPK(w3, st1[6], st1[7]);
            CVTPK(w4, st1[8], st1[9]);   CVTPK(w5, st1[10], st1[11]);
            CVTPK(w6, st1[12], st1[13]); CVTPK(w7, st1[14], st1[15]);
            PLSWAP(w0, w2); PLSWAP(w1, w3); PLSWAP(w4, w6); PLSWAP(w5, w7);
            u32x4 uA = {w0, w1, w2, w3}, uB = {w4, w5, w6, w7};
            pf2 = __builtin_bit_cast(bf16x8, uA);
            pf3 = __builtin_bit_cast(bf16x8, uB);
        }

        // O^T += mfma(V^T, P^T)
        __builtin_amdgcn_s_setprio(1);
        #pragma unroll
        for (int kc = 0; kc < 4; ++kc) {
            bf16x8 vf0 = *(const bf16x8*)(Vb + 128 * lq + 16 * ((2 * kc + hi) ^ x7));
            bf16x8 vf1 = *(const bf16x8*)(Vb + 128 * (32 + lq) + 16 * ((2 * kc + hi) ^ x7));
            bf16x8 pfv = (kc == 0) ? pf0 : (kc == 1) ? pf1 : (kc == 2) ? pf2 : pf3;
            ot0 = __builtin_amdgcn_mfma_f32_32x32x16_bf16(vf0, pfv, ot0, 0, 0, 0);
            ot1 = __builtin_amdgcn_mfma_f32_32x32x16_bf16(vf1, pfv, ot1, 0, 0, 0);
        }
        __builtin_amdgcn_s_setprio(0);

        if (t + 1 < SEQ / 64) stage_write(cur ^ 1);
        __syncthreads();
        cur ^= 1;
    }

    // epilogue: O[q][d] = O^T / l, to [B,S,DIM] bf16
    const float inv = 1.0f / l;
    const int b = bh >> 4, h = bh & 15;
    unsigned short* orow = O + ((size_t)(b * SEQ + qrow)) * DIM + h * HD;
    #pragma unroll
    for (int tg = 0; tg < 4; ++tg) {
        unsigned wA, wB;
        CVTPK(wA, ot0[4 * tg + 0] * inv, ot0[4 * tg + 1] * inv);
        CVTPK(wB, ot0[4 * tg + 2] * inv, ot0[4 * tg + 3] * inv);
        u32x2 wlo = {wA, wB};
        *(u32x2*)(orow + 8 * tg + 4 * hi) = wlo;
        CVTPK(wA, ot1[4 * tg + 0] * inv, ot1[4 * tg + 1] * inv);
        CVTPK(wB, ot1[4 * tg + 2] * inv, ot1[4 * tg + 3] * inv);
        u32x2 whi = {wA, wB};
        *(u32x2*)(orow + 32 + 8 * tg + 4 * hi) = whi;
    }
}

extern "C" void kernel_launch(void* const* d_in, const int* in_sizes, int n_in,
                              void* d_out, int out_size, void* d_ws, size_t ws_size,
                              hipStream_t stream) {
    const float* x  = (const float*)d_in[0];
    const float* Wq = (const float*)d_in[1];
    const float* Wk = (const float*)d_in[2];
    const float* Wv = (const float*)d_in[3];
    const float* Wo = (const float*)d_in[4];
    const float* bo = (const float*)d_in[5];
    float* out = (float*)d_out;

    unsigned short* ws = (unsigned short*)d_ws;
    unsigned short* xb  = ws;
    unsigned short* wqb = xb + (size_t)MTOT * DIM;
    unsigned short* wkb = wqb + (size_t)DIM * DIM;
    unsigned short* wvb = wkb + (size_t)DIM * DIM;
    unsigned short* wob = wvb + (size_t)DIM * DIM;
    unsigned short* qb  = wob + (size_t)DIM * DIM;
    unsigned short* kb  = qb + (size_t)MTOT * DIM;
    unsigned short* vb  = kb + (size_t)MTOT * DIM;
    unsigned short* vtb = vb + (size_t)MTOT * DIM;   // V^T tiled: [bh][t][d][kv]
    unsigned short* ob  = vtb + (size_t)MTOT * DIM;

    cast_all<<<dim3(8192), 256, 0, stream>>>(x, Wq, Wk, Wv, Wo, xb, wqb, wkb, wvb, wob);

    gemm_nt<0><<<dim3(DIM / 128, MTOT / 128, 3), 256, 0, stream>>>(
        xb, wqb, wkb, wvb, qb, kb, vb, nullptr, nullptr);

    vtrans_kernel<<<dim3(1024), 256, 0, stream>>>(vb, vtb);

    attn_kernel<<<dim3(256), 512, 0, stream>>>(qb, kb, vtb, ob);

    gemm_nt<1><<<dim3(DIM / 128, MTOT / 128, 1), 256, 0, stream>>>(
        ob, wob, nullptr, nullptr, nullptr, nullptr, nullptr, out, bo);
}

// Round 13
// 120.392 us; speedup vs baseline: 1.3008x; 1.0812x over previous
//
#include <hip/hip_runtime.h>
#include <hip/hip_bf16.h>

#define SEQ 2048
#define DIM 1024
#define NH 16
#define HD 64
#define MTOT 4096  // B*S

typedef __attribute__((ext_vector_type(8))) short bf16x8;
typedef __attribute__((ext_vector_type(4))) float f32x4;
typedef __attribute__((ext_vector_type(16))) float f32x16;
typedef __attribute__((ext_vector_type(4))) unsigned int u32x4;
typedef __attribute__((ext_vector_type(2))) unsigned int u32x2;

typedef const __attribute__((address_space(1))) void* gptr_t;
typedef __attribute__((address_space(3))) void* sptr_t;

static __device__ __forceinline__ unsigned short f2bf(float f) {
    unsigned int u = __builtin_bit_cast(unsigned int, f);
    return (unsigned short)((u + 0x7FFFu + ((u >> 16) & 1u)) >> 16);
}

#define CVTPK(d, x, y) asm("v_cvt_pk_bf16_f32 %0, %1, %2" : "=v"(d) : "v"(x), "v"(y))
#define PLSWAP(a, b) asm("v_permlane32_swap_b32 %0, %1" : "+v"(a), "+v"(b))

#if __has_builtin(__builtin_amdgcn_exp2f)
#define EXP2F(x) __builtin_amdgcn_exp2f(x)
#else
#define EXP2F(x) exp2f(x)
#endif

// ---------------- fused fp32 -> bf16 cast (x + 4 weights, one launch) ----------------
__global__ __launch_bounds__(256) void cast_all(
    const float* __restrict__ x,  const float* __restrict__ wq,
    const float* __restrict__ wk, const float* __restrict__ wv,
    const float* __restrict__ wo,
    unsigned short* __restrict__ xb,  unsigned short* __restrict__ wqb,
    unsigned short* __restrict__ wkb, unsigned short* __restrict__ wvb,
    unsigned short* __restrict__ wob)
{
    int bid = blockIdx.x;
    const float* src;
    unsigned short* dst;
    int boff;
    if (bid < 4096) { src = x; dst = xb; boff = bid; }
    else {
        int w = (bid - 4096) >> 10, r = (bid - 4096) & 1023;
        src = (w == 0) ? wq : (w == 1) ? wk : (w == 2) ? wv : wo;
        dst = (w == 0) ? wqb : (w == 1) ? wkb : (w == 2) ? wvb : wob;
        boff = r;
    }
    size_t i = ((size_t)boff * 256 + threadIdx.x) * 4;
    float4 v = *reinterpret_cast<const float4*>(src + i);
    ushort4 o;
    o.x = f2bf(v.x); o.y = f2bf(v.y); o.z = f2bf(v.z); o.w = f2bf(v.w);
    *reinterpret_cast<ushort4*>(dst + i) = o;
}

// ---------------- NT GEMM: C[M,N] = A[M,K] * B[N,K]^T (bf16 in) ----------------
// MODE 0: z in {0,1,2} selects B/W and dst (q/k/v); scatter to [B,H,S,hd], Q scaled 0.125*log2e.
// MODE 1: fp32 out + bias.
template<int MODE>
__global__ __launch_bounds__(256) void gemm_nt(
    const unsigned short* __restrict__ A,
    const unsigned short* __restrict__ B0,
    const unsigned short* __restrict__ B1,
    const unsigned short* __restrict__ B2,
    unsigned short* __restrict__ D0,
    unsigned short* __restrict__ D1,
    unsigned short* __restrict__ D2,
    float* __restrict__ Df,
    const float* __restrict__ bias)
{
    constexpr int K = DIM;
    __shared__ __align__(16) unsigned short Asm[128 * 32];
    __shared__ __align__(16) unsigned short Bsm[128 * 32];

    const int tid = threadIdx.x;
    const int wave = tid >> 6, lane = tid & 63;
    const int wm = wave >> 1, wn = wave & 1;
    const int m0 = blockIdx.y * 128, n0 = blockIdx.x * 128;
    const int fr = lane & 15;

    const unsigned short* Bsel = (MODE == 1 || blockIdx.z == 0) ? B0 : (blockIdx.z == 1 ? B1 : B2);

    const int srow = wave * 32 + (lane >> 2);
    const int schunk = (lane & 3) ^ ((lane >> 3) & 3);
    const size_t abase = (size_t)(m0 + srow) * K + (size_t)schunk * 8;
    const size_t bbase = (size_t)(n0 + srow) * K + (size_t)schunk * 8;

    f32x4 acc[4][4] = {};

    for (int k0 = 0; k0 < K; k0 += 32) {
        #pragma unroll
        for (int c = 0; c < 2; ++c) {
            __builtin_amdgcn_global_load_lds(
                (gptr_t)(A + abase + (size_t)c * 16 * K + k0),
                (sptr_t)((char*)Asm + wave * 2048 + c * 1024), 16, 0, 0);
            __builtin_amdgcn_global_load_lds(
                (gptr_t)(Bsel + bbase + (size_t)c * 16 * K + k0),
                (sptr_t)((char*)Bsm + wave * 2048 + c * 1024), 16, 0, 0);
        }
        __syncthreads();

        bf16x8 af[4], bf[4];
        const int ca = ((lane >> 4) ^ ((fr >> 1) & 3)) * 16;
        #pragma unroll
        for (int i = 0; i < 4; ++i) {
            int ra = wm * 64 + i * 16 + fr;
            int rb = wn * 64 + i * 16 + fr;
            af[i] = *(const bf16x8*)((const char*)Asm + ra * 64 + ca);
            bf[i] = *(const bf16x8*)((const char*)Bsm + rb * 64 + ca);
        }
        #pragma unroll
        for (int i = 0; i < 4; ++i)
            #pragma unroll
            for (int j = 0; j < 4; ++j)
                acc[i][j] = __builtin_amdgcn_mfma_f32_16x16x32_bf16(af[i], bf[j], acc[i][j], 0, 0, 0);
        __syncthreads();
    }

    if (MODE == 0) {
        unsigned short* Dst = (blockIdx.z == 0) ? D0 : (blockIdx.z == 1 ? D1 : D2);
        // Q gets 1/8 * log2(e) folded in (softmax runs in exp2 domain)
        const float scale = (blockIdx.z == 0) ? 0.1803368787f : 1.0f;
        #pragma unroll
        for (int i = 0; i < 4; ++i)
            #pragma unroll
            for (int j = 0; j < 4; ++j)
                #pragma unroll
                for (int r = 0; r < 4; ++r) {
                    int m = m0 + wm * 64 + i * 16 + (lane >> 4) * 4 + r;
                    int n = n0 + wn * 64 + j * 16 + fr;
                    int b = m >> 11, s = m & 2047, h = n >> 6, dh = n & 63;
                    Dst[(((size_t)(b * NH + h)) * SEQ + s) * HD + dh] = f2bf(acc[i][j][r] * scale);
                }
    } else {
        #pragma unroll
        for (int i = 0; i < 4; ++i)
            #pragma unroll
            for (int j = 0; j < 4; ++j)
                #pragma unroll
                for (int r = 0; r < 4; ++r) {
                    int m = m0 + wm * 64 + i * 16 + (lane >> 4) * 4 + r;
                    int n = n0 + wn * 64 + j * 16 + fr;
                    Df[(size_t)m * DIM + n] = acc[i][j][r] + bias[n];
                }
    }
}

// ---------------- V transpose: [bh][s][d] -> tiled V^T [bh][t=s/64][d][kv=s&63] ----------------
__global__ __launch_bounds__(256) void vtrans_kernel(
    const unsigned short* __restrict__ V, unsigned short* __restrict__ Vt)
{
    __shared__ __align__(16) unsigned short T[64 * 66];
    const int bh = blockIdx.x >> 5, t = blockIdx.x & 31;
    const unsigned short* src = V + ((size_t)bh * SEQ + t * 64) * HD;
    const int tid = threadIdx.x;

    #pragma unroll
    for (int it = 0; it < 2; ++it) {
        int vt = tid + it * 256;
        int kvp = vt >> 4, sub = vt & 1, dch = (vt >> 1) & 7;
        bf16x8 sv = *(const bf16x8*)(src + (size_t)(2 * kvp + sub) * HD + dch * 8);
        u32x4 vw = __builtin_bit_cast(u32x4, sv);
        unsigned p0 = (unsigned)__shfl_xor((int)vw[0], 1);
        unsigned p1 = (unsigned)__shfl_xor((int)vw[1], 1);
        unsigned p2 = (unsigned)__shfl_xor((int)vw[2], 1);
        unsigned p3 = (unsigned)__shfl_xor((int)vw[3], 1);
        unsigned ea0 = sub ? p2 : vw[0];
        unsigned ea1 = sub ? p3 : vw[1];
        unsigned eb0 = sub ? vw[2] : p0;
        unsigned eb1 = sub ? vw[3] : p1;
        unsigned* vp = (unsigned*)&T[0];
        const int dbase = dch * 8 + sub * 4;
        vp[33 * (dbase + 0) + kvp] = (ea0 & 0xffffu) | (eb0 << 16);
        vp[33 * (dbase + 1) + kvp] = (ea0 >> 16) | (eb0 & 0xffff0000u);
        vp[33 * (dbase + 2) + kvp] = (ea1 & 0xffffu) | (eb1 << 16);
        vp[33 * (dbase + 3) + kvp] = (ea1 >> 16) | (eb1 & 0xffff0000u);
    }
    __syncthreads();

    const int drow = tid >> 2, kch = tid & 3;
    unsigned short* dst = Vt + (((size_t)(bh * 32 + t) * 64) << 6);
    bf16x8 a = *(const bf16x8*)((const char*)&T[0] + 132 * drow + 16 * kch);
    bf16x8 b = *(const bf16x8*)((const char*)&T[0] + 132 * drow + 16 * kch + 64);
    *(bf16x8*)(dst + drow * 64 + kch * 8) = a;
    *(bf16x8*)(dst + drow * 64 + (kch + 4) * 8) = b;
}

// ---------------- flash attention: static-max, b128 XOR-swz LDS, 2-way kv-split ----------------
// grid: 512 blocks x 512 threads (2 blocks/CU, 4 waves/SIMD). Block = 256 q-rows x 1024 kv.
// Static softmax (max factors out entirely) => partials linear: merge = (ot_a+ot_b)/(l_a+l_b).
__global__ __launch_bounds__(512, 4) void attn_kernel(
    const unsigned short* __restrict__ Q,
    const unsigned short* __restrict__ Kg,
    const unsigned short* __restrict__ Vt,
    float* __restrict__ po,   // [2*32][2048][64] f32 unnormalized partial O
    float* __restrict__ ml)   // [2*32*2048] f32 partial l
{
    __shared__ __align__(16) unsigned short Ksm[2][64 * 64];  // [kv][d], 128B rows, XOR-swz
    __shared__ __align__(16) unsigned short Vsm[2][64 * 64];  // [d][kv], 128B rows, XOR-swz

    const int tid = threadIdx.x;
    const int wave = tid >> 6, lane = tid & 63;
    const int lq = lane & 31, hi = lane >> 5;

    const int bid = blockIdx.x;
    const int xcd = bid & 7, slot = bid >> 3;          // slot 0..63
    const int bh = xcd * 4 + (slot & 3);
    const int rest = slot >> 2;                        // 0..15
    const int q0 = (rest >> 1) * 256;
    const int half = rest & 1;
    const int kvbase = half * 1024;

    const unsigned short* Qh = Q + (size_t)bh * SEQ * HD;
    const unsigned short* Kh = Kg + (size_t)bh * SEQ * HD;
    const unsigned short* Vh = Vt + (size_t)bh * SEQ * HD;   // tiled: + t64*64 + d*64 + kv

    const int qrow = q0 + wave * 32 + lq;
    bf16x8 qf[4];
    #pragma unroll
    for (int dch = 0; dch < 4; ++dch)
        qf[dch] = *(const bf16x8*)(Qh + (size_t)qrow * HD + dch * 16 + hi * 8);

    f32x16 ot0 = {}, ot1 = {};          // O^T rows d=0..31 / 32..63, col q=lq
    float l = 0.f;

    // staging map: row = tid>>3 (0..63), chunk = tid&7; same for K and V tiles
    const int srow = tid >> 3, sch = tid & 7;
    const int swoff = 128 * srow + 16 * (sch ^ (srow & 7));   // swizzled LDS byte offset

    bf16x8 sk, sv;
    auto stage_load = [&](int t64) {
        sk = *(const bf16x8*)(Kh + (size_t)(t64 + srow) * HD + sch * 8);
        sv = *(const bf16x8*)(Vh + (size_t)t64 * 64 + srow * 64 + sch * 8);
    };
    auto stage_write = [&](int buf) {
        *(bf16x8*)((char*)&Ksm[buf][0] + swoff) = sk;
        *(bf16x8*)((char*)&Vsm[buf][0] + swoff) = sv;
    };

    stage_load(kvbase);
    stage_write(0);
    __syncthreads();

    const int x7 = lq & 7;   // (lq&7) == ((32+lq)&7)

    int cur = 0;
    #pragma unroll 1
    for (int t = 0; t < 16; ++t) {
        if (t < 15) stage_load(kvbase + (t + 1) * 64);   // T14: issue loads early

        const char* Kb = (const char*)&Ksm[cur][0];
        const char* Vb = (const char*)&Vsm[cur][0];

        // S^T = mfma(K, Q^T); static softmax: exp2 directly (constant shift cancels in O = num/den)
        f32x16 st0 = {}, st1 = {};
        __builtin_amdgcn_s_setprio(1);
        #pragma unroll
        for (int dch = 0; dch < 4; ++dch) {
            bf16x8 kf0 = *(const bf16x8*)(Kb + 128 * lq + 16 * ((2 * dch + hi) ^ x7));
            bf16x8 kf1 = *(const bf16x8*)(Kb + 128 * (32 + lq) + 16 * ((2 * dch + hi) ^ x7));
            st0 = __builtin_amdgcn_mfma_f32_32x32x16_bf16(kf0, qf[dch], st0, 0, 0, 0);
            st1 = __builtin_amdgcn_mfma_f32_32x32x16_bf16(kf1, qf[dch], st1, 0, 0, 0);
        }
        __builtin_amdgcn_s_setprio(0);

        // P = exp2(S - 12); 4-way partial sums for ILP
        float sa = 0.f, sb = 0.f, sc = 0.f, sd = 0.f;
        #pragma unroll
        for (int r = 0; r < 16; r += 4) {
            st0[r]     = EXP2F(st0[r] - 12.0f);     sa += st0[r];
            st0[r + 1] = EXP2F(st0[r + 1] - 12.0f); sb += st0[r + 1];
            st0[r + 2] = EXP2F(st0[r + 2] - 12.0f); sc += st0[r + 2];
            st0[r + 3] = EXP2F(st0[r + 3] - 12.0f); sd += st0[r + 3];
        }
        #pragma unroll
        for (int r = 0; r < 16; r += 4) {
            st1[r]     = EXP2F(st1[r] - 12.0f);     sa += st1[r];
            st1[r + 1] = EXP2F(st1[r + 1] - 12.0f); sb += st1[r + 1];
            st1[r + 2] = EXP2F(st1[r + 2] - 12.0f); sc += st1[r + 2];
            st1[r + 3] = EXP2F(st1[r + 3] - 12.0f); sd += st1[r + 3];
        }
        float ps = (sa + sb) + (sc + sd);
        ps += __shfl_xor(ps, 32);
        l += ps;

        // T12: P -> bf16 B-frags fully in-register (cvt_pk + permlane32_swap)
        bf16x8 pf0, pf1, pf2, pf3;
        {
            unsigned w0, w1, w2, w3, w4, w5, w6, w7;
            CVTPK(w0, st0[0], st0[1]);   CVTPK(w1, st0[2], st0[3]);
            CVTPK(w2, st0[4], st0[5]);   CVTPK(w3, st0[6], st0[7]);
            CVTPK(w4, st0[8], st0[9]);   CVTPK(w5, st0[10], st0[11]);
            CVTPK(w6, st0[12], st0[13]); CVTPK(w7, st0[14], st0[15]);
            PLSWAP(w0, w2); PLSWAP(w1, w3); PLSWAP(w4, w6); PLSWAP(w5, w7);
            u32x4 uA = {w0, w1, w2, w3}, uB = {w4, w5, w6, w7};
            pf0 = __builtin_bit_cast(bf16x8, uA);
            pf1 = __builtin_bit_cast(bf16x8, uB);
        }
        {
            unsigned w0, w1, w2, w3, w4, w5, w6, w7;
            CVTPK(w0, st1[0], st1[1]);   CVTPK(w1, st1[2], st1[3]);
            CVTPK(w2, st1[4], st1[5]);   CVTPK(w3, st1[6], st1[7]);
            CVTPK(w4, st1[8], st1[9]);   CVTPK(w5, st1[10], st1[11]);
            CVTPK(w6, st1[12], st1[13]); CVTPK(w7, st1[14], st1[15]);
            PLSWAP(w0, w2); PLSWAP(w1, w3); PLSWAP(w4, w6); PLSWAP(w5, w7);
            u32x4 uA = {w0, w1, w2, w3}, uB = {w4, w5, w6, w7};
            pf2 = __builtin_bit_cast(bf16x8, uA);
            pf3 = __builtin_bit_cast(bf16x8, uB);
        }

        // O^T += mfma(V^T, P^T)
        __builtin_amdgcn_s_setprio(1);
        #pragma unroll
        for (int kc = 0; kc < 4; ++kc) {
            bf16x8 vf0 = *(const bf16x8*)(Vb + 128 * lq + 16 * ((2 * kc + hi) ^ x7));
            bf16x8 vf1 = *(const bf16x8*)(Vb + 128 * (32 + lq) + 16 * ((2 * kc + hi) ^ x7));
            bf16x8 pfv = (kc == 0) ? pf0 : (kc == 1) ? pf1 : (kc == 2) ? pf2 : pf3;
            ot0 = __builtin_amdgcn_mfma_f32_32x32x16_bf16(vf0, pfv, ot0, 0, 0, 0);
            ot1 = __builtin_amdgcn_mfma_f32_32x32x16_bf16(vf1, pfv, ot1, 0, 0, 0);
        }
        __builtin_amdgcn_s_setprio(0);

        if (t < 15) stage_write(cur ^ 1);
        __syncthreads();
        cur ^= 1;
    }

    // ---- write partials (unnormalized O^T + l); merge is linear under static max ----
    const size_t prow = (size_t)(half * 32 + bh) * SEQ + qrow;
    float* por = po + prow * 64;
    #pragma unroll
    for (int tg = 0; tg < 4; ++tg) {
        f32x4 v0 = {ot0[4 * tg + 0], ot0[4 * tg + 1], ot0[4 * tg + 2], ot0[4 * tg + 3]};
        *(f32x4*)(por + 8 * tg + 4 * hi) = v0;
        f32x4 v1 = {ot1[4 * tg + 0], ot1[4 * tg + 1], ot1[4 * tg + 2], ot1[4 * tg + 3]};
        *(f32x4*)(por + 32 + 8 * tg + 4 * hi) = v1;
    }
    if (hi == 0) ml[prow] = l;
}

// ---------------- merge kv-half partials -> bf16 O [B,S,DIM] ----------------
__global__ __launch_bounds__(256) void merge_kernel(
    const float* __restrict__ po,
    const float* __restrict__ ml,
    unsigned short* __restrict__ ob)
{
    const int gid = blockIdx.x * 256 + threadIdx.x;   // 524288
    const int row = gid >> 3, dch = gid & 7;          // row = bh*2048 + s
    const size_t p1 = row, p2 = (size_t)32 * SEQ + row;
    const float inv = 1.0f / (ml[p1] + ml[p2]);

    f32x4 a0 = *(const f32x4*)(po + p1 * 64 + dch * 8);
    f32x4 a1 = *(const f32x4*)(po + p1 * 64 + dch * 8 + 4);
    f32x4 b0 = *(const f32x4*)(po + p2 * 64 + dch * 8);
    f32x4 b1 = *(const f32x4*)(po + p2 * 64 + dch * 8 + 4);

    unsigned wA, wB, wC, wD;
    CVTPK(wA, (a0[0] + b0[0]) * inv, (a0[1] + b0[1]) * inv);
    CVTPK(wB, (a0[2] + b0[2]) * inv, (a0[3] + b0[3]) * inv);
    CVTPK(wC, (a1[0] + b1[0]) * inv, (a1[1] + b1[1]) * inv);
    CVTPK(wD, (a1[2] + b1[2]) * inv, (a1[3] + b1[3]) * inv);
    u32x4 w = {wA, wB, wC, wD};

    const int bh = row >> 11, s = row & 2047;
    const int b = bh >> 4, h = bh & 15;
    *(u32x4*)(ob + ((size_t)(b * SEQ + s)) * DIM + h * HD + dch * 8) = w;
}

extern "C" void kernel_launch(void* const* d_in, const int* in_sizes, int n_in,
                              void* d_out, int out_size, void* d_ws, size_t ws_size,
                              hipStream_t stream) {
    const float* x  = (const float*)d_in[0];
    const float* Wq = (const float*)d_in[1];
    const float* Wk = (const float*)d_in[2];
    const float* Wv = (const float*)d_in[3];
    const float* Wo = (const float*)d_in[4];
    const float* bo = (const float*)d_in[5];
    float* out = (float*)d_out;

    unsigned short* ws = (unsigned short*)d_ws;
    unsigned short* xb  = ws;
    unsigned short* wqb = xb + (size_t)MTOT * DIM;
    unsigned short* wkb = wqb + (size_t)DIM * DIM;
    unsigned short* wvb = wkb + (size_t)DIM * DIM;
    unsigned short* wob = wvb + (size_t)DIM * DIM;
    unsigned short* qb  = wob + (size_t)DIM * DIM;
    unsigned short* kb  = qb + (size_t)MTOT * DIM;
    unsigned short* vb  = kb + (size_t)MTOT * DIM;
    unsigned short* vtb = vb + (size_t)MTOT * DIM;   // V^T tiled: [bh][t][d][kv]
    unsigned short* ob  = vtb + (size_t)MTOT * DIM;
    float* po = (float*)(ob + (size_t)MTOT * DIM);   // [2*32*2048][64] f32
    float* ml = po + (size_t)2 * 32 * SEQ * 64;      // [2*32*2048] f32

    cast_all<<<dim3(8192), 256, 0, stream>>>(x, Wq, Wk, Wv, Wo, xb, wqb, wkb, wvb, wob);

    gemm_nt<0><<<dim3(DIM / 128, MTOT / 128, 3), 256, 0, stream>>>(
        xb, wqb, wkb, wvb, qb, kb, vb, nullptr, nullptr);

    vtrans_kernel<<<dim3(1024), 256, 0, stream>>>(vb, vtb);

    attn_kernel<<<dim3(512), 512, 0, stream>>>(qb, kb, vtb, po, ml);

    merge_kernel<<<dim3(2048), 256, 0, stream>>>(po, ml, ob);

    gemm_nt<1><<<dim3(DIM / 128, MTOT / 128, 1), 256, 0, stream>>>(
        ob, wob, nullptr, nullptr, nullptr, nullptr, nullptr, out, bo);
}